// Round 8
// baseline (376.194 us; speedup 1.0000x reference)
//
#include <hip/hip_runtime.h>

// B=4, Cin=Cout=64, H=W=128, K=9, PAD=1. NCHW fp32.
//
// lgkm-only barrier: LDS producer->consumer needs lgkmcnt(0) only; global
// prefetch loads stay in flight across it (vmcnt wait lands at the use).
#define BAR_LGKM()                                         \
  do {                                                     \
    asm volatile("s_waitcnt lgkmcnt(0)" ::: "memory");     \
    __builtin_amdgcn_s_barrier();                          \
  } while (0)

// XCD-aware swizzle: 1024 blocks, 8 XCDs, dispatch round-robins bid%8.
// Each XCD gets a contiguous 128-block chunk -> gather footprint ~2.4MB
// fits the XCD's 4MB L2. (Verified round 4: FETCH 52.6 MB -> 12.7 MB.)
__device__ __forceinline__ int swz_block(int bid) {
  return ((bid & 7) << 7) + (bid >> 3);
}

// Phase-stagger: co-resident blocks (4/CU; XCD = bid%8, CU fill round-robin
// over bid/8 mod 32) differ only in blockIdx bits 8-9. All blocks run
// identical barrier-locked iterations, so without a stagger the whole CU
// convoys: VALU window and memory window alternate CU-wide and ADD instead
// of overlapping (VALUBusy 44% with no saturated pipe, rounds 3-7).
// A one-time entry delay of lag*~700cy puts co-resident blocks in antiphase.
__device__ __forceinline__ void stagger_entry() {
  int n = (((int)blockIdx.x >> 8) & 3) * 44;   // 44 iters x ~16cy = ~700cy/step
  float z = 1.0f + (float)threadIdx.x * 1e-7f;
#pragma unroll 1
  for (int i = 0; i < n; ++i) {
    z = fmaf(z, 1.0000001f, 1e-7f);
    z = fmaf(z, 1.0000001f, 1e-7f);
    z = fmaf(z, 1.0000001f, 1e-7f);
    z = fmaf(z, 1.0000001f, 1e-7f);
  }
  asm volatile("" :: "v"(z));                  // keep the chain alive
}

// Workspace layout (floats):
//   wt1  @ 0       (36864)  main weights layer1, [c][og][k][oi] (og=o/8, oi=o%8)
//   wt2  @ 36864   (36864)
//   wo1  @ 73728   (10368)  offset-conv weights layer1, [c][t][j] (j=0..17)
//   wo2  @ 84096   (10368)
//   bn1  @ 94464   (128)    scale[64], shift[64]
//   bn2  @ 94592   (128)
//   offb @ 94720   (1179648)  4*18*16384
//   hbuf @ 1274368 (4194304)  4*64*16384

// ---------------- prep: weight relayouts + BN constants ---------------------
__global__ __launch_bounds__(256) void prep_kernel(
    const float* __restrict__ w1, const float* __restrict__ w2,
    const float* __restrict__ woff1, const float* __restrict__ woff2,
    const float* __restrict__ g1, const float* __restrict__ be1,
    const float* __restrict__ m1, const float* __restrict__ v1,
    const float* __restrict__ g2, const float* __restrict__ be2,
    const float* __restrict__ m2, const float* __restrict__ v2,
    float* __restrict__ ws) {
  float* wt1 = ws;
  float* wt2 = ws + 36864;
  float* wo1 = ws + 73728;
  float* wo2 = ws + 84096;
  float* bn1 = ws + 94464;
  float* bn2 = ws + 94592;
  int idx = blockIdx.x * 256 + threadIdx.x;
  if (idx < 73728) {
    int t = (idx < 36864) ? idx : idx - 36864;
    const float* w = (idx < 36864) ? w1 : w2;
    float* wt = (idx < 36864) ? wt1 : wt2;
    int oi = t & 7;
    int rest = t >> 3;             // (c*8+og)*9 + k
    int k = rest % 9;
    int cog = rest / 9;
    int og = cog & 7, c = cog >> 3;
    int o = og * 8 + oi;
    wt[t] = w[(o * 64 + c) * 9 + k];
  } else if (idx < 94464) {
    int u = idx - 73728;
    int t2 = (u < 10368) ? u : u - 10368;
    const float* w = (u < 10368) ? woff1 : woff2;
    float* wo = (u < 10368) ? wo1 : wo2;
    int j = t2 % 18;
    int v = t2 / 18;               // c*9 + t
    int tt = v % 9;
    int c = v / 9;
    wo[t2] = w[(j * 64 + c) * 9 + tt];
  } else if (idx < 94528) {
    int o = idx - 94464;
    float s = g1[o] * rsqrtf(v1[o] + 1e-5f);
    bn1[o] = s;
    bn1[64 + o] = be1[o] - m1[o] * s;
  } else if (idx < 94592) {
    int o = idx - 94528;
    float s = g2[o] * rsqrtf(v2[o] + 1e-5f);
    bn2[o] = s;
    bn2[64 + o] = be2[o] - m2[o] * s;
  }
}

// ---------------- offset conv: 3x3, 64 -> 18 ch, zero pad -------------------
// (round-4 structure + entry stagger)
__global__ __launch_bounds__(512, 8) void conv_off_kernel(
    const float* __restrict__ xin, const float* __restrict__ wofft,
    const float* __restrict__ boff, float* __restrict__ off) {
  __shared__ float halo[2][792];   // [buf][plane*198 + pos], 4 planes/stage
  stagger_entry();
  int tid = threadIdx.x;
  int pxl = tid & 63;
  int og = tid >> 6;
  int ogu = __builtin_amdgcn_readfirstlane(og);   // wave-uniform -> s_loads
  int p0 = swz_block(blockIdx.x) * 64;
  int b = p0 >> 14, hw0 = p0 & 16383;
  int h = hw0 >> 7, w0 = hw0 & 127;

  bool sv = tid < 396;
  int pp = (tid >= 198) ? 1 : 0;   // which of 2 plane-slots this thread loads
  int pos = tid - pp * 198;
  int r = pos / 66, cc = pos - r * 66;
  int yy = h + r - 1, xx = w0 + cc - 1;
  bool inb = sv && (yy >= 0) && (yy < 128) && (xx >= 0) && (xx < 128);
  int ofs = (yy << 7) + xx;        // plane-relative
  const float* xb0 = xin + ((size_t)(b * 64) << 14);

  // prologue: planes 0..3 (thread covers planes pp and 2+pp at its pos)
  float stg0 = inb ? xb0[((size_t)pp << 14) + ofs] : 0.f;
  float stg1 = inb ? xb0[((size_t)(2 + pp) << 14) + ofs] : 0.f;

  // j-channel assignment: og 0,1 -> 3 outputs; og 2..7 -> 2 outputs.
  int jbase = (ogu < 2) ? ogu * 3 : 6 + (ogu - 2) * 2;
  int nj = (ogu < 2) ? 3 : 2;
  int jc2 = jbase + 2;
  if (jc2 > 17) jc2 = 17;          // clamp (result unused when nj==2)

  float acc[3] = {0.f, 0.f, 0.f};

#pragma unroll 1
  for (int cg = 0; cg < 64; cg += 4) {
    int bufi = (cg >> 2) & 1;
    if (sv) {
      halo[bufi][pp * 198 + pos] = stg0;
      halo[bufi][(2 + pp) * 198 + pos] = stg1;
    }
    if (cg < 60) {
      stg0 = inb ? xb0[((size_t)(cg + 4 + pp) << 14) + ofs] : 0.f;
      stg1 = inb ? xb0[((size_t)(cg + 6 + pp) << 14) + ofs] : 0.f;
    }
    BAR_LGKM();
    const float* hb = halo[bufi];
#pragma unroll
    for (int p = 0; p < 4; ++p) {
      const float* wc = wofft + (cg + p) * 162;
#pragma unroll
      for (int t = 0; t < 9; ++t) {
        float v = hb[p * 198 + (t / 3) * 66 + pxl + (t % 3)];
        acc[0] = fmaf(v, wc[t * 18 + jbase], acc[0]);
        acc[1] = fmaf(v, wc[t * 18 + jbase + 1], acc[1]);
        acc[2] = fmaf(v, wc[t * 18 + jc2], acc[2]);
      }
    }
  }
#pragma unroll
  for (int i = 0; i < 3; ++i) {
    if (i < nj) {
      int j = jbase + i;
      off[((size_t)(b * 18 + j) << 14) + hw0 + pxl] = acc[i] + boff[j];
    }
  }
}

// ---------------- fused deformable sample + einsum + BN + ReLU --------------
// Round-7 structure (folded coeffs, incrementing pointers, s_load weights,
// depth-1 prefetch across lgkm-only barrier, XCD swizzle) + entry stagger.
__global__ __launch_bounds__(512, 8) void dcn_main_kernel(
    const float* __restrict__ xin, const float* __restrict__ off,
    const float* __restrict__ wt, const float* __restrict__ bn,
    float* __restrict__ out) {
  __shared__ float sbuf[2][576];
  stagger_entry();
  int tid = threadIdx.x;
  int pxl = tid & 63;
  int og = tid >> 6;
  int ogu = __builtin_amdgcn_readfirstlane(og);
  int p0 = swz_block(blockIdx.x) * 64;
  int b = p0 >> 14, hw0 = p0 & 16383;
  int h = hw0 >> 7, w0 = hw0 & 127;
  const float* xb = xin + ((size_t)b << 20);

  bool act1 = (tid & 7) == 0;      // slot1 handled by 1/8 of threads
  int s1 = 512 + (tid >> 3);       // slot id 512..575 (k=8)

  // --- per-slot params: folded coeffs (x-select baked in) + row pointers ---
  float q[2][4];                   // [slot][{t0.x,t0.y,t1.x,t1.y} coeff]
  const float* pa[2];              // row y0 float2 base (per-lane), plane 0
  const float* pb[2];              // row y1

#pragma unroll
  for (int j = 0; j < 2; ++j) {
    bool a = (j == 0) || act1;
    int s = (j == 0) ? tid : s1;
    int k = s >> 6;
    int pxs = s & 63;
    int hw = hw0 + pxs;
    float dy = a ? off[((size_t)(b * 18 + 2 * k) << 14) + hw] : 0.f;
    float dx = a ? off[((size_t)(b * 18 + 2 * k + 1) << 14) + hw] : 0.f;
    float py = (float)(h + k / 3 - 1) + dy;
    float pxf = (float)(w0 + pxs + k % 3 - 1) + dx;
    float y0f = floorf(py), x0f = floorf(pxf);
    float wy1 = py - y0f, wx1 = pxf - x0f;
    float wy0 = 1.f - wy1, wx0 = 1.f - wx1;
    int y0 = (int)y0f, x0 = (int)x0f;
    int y1 = y0 + 1, x1 = x0 + 1;
    bool vy0 = (y0 >= 0) && (y0 <= 127);
    bool vy1 = (y1 >= 0) && (y1 <= 127);
    bool vx0 = (x0 >= 0) && (x0 <= 127);
    bool vx1 = (x1 >= 0) && (x1 <= 127);
    float pw0 = (vy0 && vx0) ? wy0 * wx0 : 0.f;
    float pw1 = (vy0 && vx1) ? wy0 * wx1 : 0.f;
    float pw2 = (vy1 && vx0) ? wy1 * wx0 : 0.f;
    float pw3 = (vy1 && vx1) ? wy1 * wx1 : 0.f;
    int y0c = min(max(y0, 0), 127), y1c = min(max(y1, 0), 127);
    int xb2 = min(max(x0, 0), 126);
    bool se0 = (x0 == xb2);        // tap(x0) is .x of the pair
    bool se1 = (x0 + 1 == xb2);    // tap(x0+1) is .x of the pair (x0==-1 case)
    // fold selects: coeff(.x) = se?pw ; coeff(.y) = !se?pw. Whenever the
    // "wrong" element is picked, the corresponding pw is already 0.
    q[j][0] = (se0 ? pw0 : 0.f) + (se1 ? pw1 : 0.f);
    q[j][1] = (se0 ? 0.f : pw0) + (se1 ? 0.f : pw1);
    q[j][2] = (se0 ? pw2 : 0.f) + (se1 ? pw3 : 0.f);
    q[j][3] = (se0 ? 0.f : pw2) + (se1 ? 0.f : pw3);
    pa[j] = xb + ((y0c << 7) + xb2);
    pb[j] = xb + ((y1c << 7) + xb2);
  }

  // prologue: taps for c=0; then advance pointers to plane 1
  float2 t0a = *(const float2*)pa[0];
  float2 t1a = *(const float2*)pb[0];
  float2 t0b = act1 ? *(const float2*)pa[1] : make_float2(0.f, 0.f);
  float2 t1b = act1 ? *(const float2*)pb[1] : make_float2(0.f, 0.f);
  pa[0] += 16384; pb[0] += 16384; pa[1] += 16384; pb[1] += 16384;

  float acc[8];
#pragma unroll
  for (int oi = 0; oi < 8; ++oi) acc[oi] = 0.f;

#pragma unroll 1
  for (int c = 0; c < 64; ++c) {
    // blend + stash to LDS (4 FMA, no selects)
    sbuf[c & 1][tid] = fmaf(q[0][0], t0a.x,
                       fmaf(q[0][1], t0a.y,
                       fmaf(q[0][2], t1a.x, q[0][3] * t1a.y)));
    if (act1) {
      sbuf[c & 1][s1] = fmaf(q[1][0], t0b.x,
                        fmaf(q[1][1], t0b.y,
                        fmaf(q[1][2], t1b.x, q[1][3] * t1b.y)));
    }
    // prefetch taps for c+1 (in flight across the lgkm barrier)
    if (c < 63) {
      t0a = *(const float2*)pa[0];
      t1a = *(const float2*)pb[0];
      if (act1) {
        t0b = *(const float2*)pa[1];
        t1b = *(const float2*)pb[1];
      }
      pa[0] += 16384; pb[0] += 16384; pa[1] += 16384; pb[1] += 16384;
    }
    BAR_LGKM();
    const float* wc = wt + (c * 8 + ogu) * 72;   // [c][og][k][8], s_load
#pragma unroll
    for (int k = 0; k < 9; ++k) {
      float sval = sbuf[c & 1][k * 64 + pxl];
#pragma unroll
      for (int oi = 0; oi < 8; ++oi)
        acc[oi] = fmaf(sval, wc[k * 8 + oi], acc[oi]);
    }
  }

#pragma unroll
  for (int oi = 0; oi < 8; ++oi) {
    int o = ogu * 8 + oi;
    float rres = fmaf(acc[oi], bn[o], bn[64 + o]);
    out[((size_t)(b * 64 + o) << 14) + hw0 + pxl] = fmaxf(rres, 0.f);
  }
}

extern "C" void kernel_launch(void* const* d_in, const int* in_sizes, int n_in,
                              void* d_out, int out_size, void* d_ws, size_t ws_size,
                              hipStream_t stream) {
  const float* x      = (const float*)d_in[0];
  const float* w_off1 = (const float*)d_in[1];
  const float* b_off1 = (const float*)d_in[2];
  const float* w1     = (const float*)d_in[3];
  const float* g1     = (const float*)d_in[4];
  const float* be1    = (const float*)d_in[5];
  const float* m1     = (const float*)d_in[6];
  const float* v1     = (const float*)d_in[7];
  const float* w_off2 = (const float*)d_in[8];
  const float* b_off2 = (const float*)d_in[9];
  const float* w2     = (const float*)d_in[10];
  const float* g2     = (const float*)d_in[11];
  const float* be2    = (const float*)d_in[12];
  const float* m2     = (const float*)d_in[13];
  const float* v2     = (const float*)d_in[14];
  float* out = (float*)d_out;

  float* ws   = (float*)d_ws;
  float* wt1  = ws;
  float* wt2  = ws + 36864;
  float* wo1  = ws + 73728;
  float* wo2  = ws + 84096;
  float* bn1  = ws + 94464;
  float* bn2  = ws + 94592;
  float* offb = ws + 94720;
  float* hbuf = ws + 1274368;

  prep_kernel<<<370, 256, 0, stream>>>(w1, w2, w_off1, w_off2,
                                       g1, be1, m1, v1, g2, be2, m2, v2, ws);

  conv_off_kernel<<<1024, 512, 0, stream>>>(x, wo1, b_off1, offb);
  dcn_main_kernel<<<1024, 512, 0, stream>>>(x, offb, wt1, bn1, hbuf);

  conv_off_kernel<<<1024, 512, 0, stream>>>(hbuf, wo2, b_off2, offb);
  dcn_main_kernel<<<1024, 512, 0, stream>>>(hbuf, offb, wt2, bn2, out);
}